// Round 9
// baseline (101.212 us; speedup 1.0000x reference)
//
#include <hip/hip_runtime.h>

#define CHUNK 256
#define MM 50
#define KK 4
#define STATE 200       // MM*KK
#define ASTRIDE 51      // odd WORD stride: bank = (19c+m) mod 32 -> all 32 banks
#define SUP 32          // chunks per super-chunk
#define NSMAX 26        // max super-chunks
#define GMAX 1024

// Dataflow protocol: publishers store epoch_s*(v+1) (v >= 0 always), readers
// poll until epoch_s*r >= 0.5. .bss zero-init = not-ready; sign flips per
// replay epoch so NO resets, NO flags, NO vmcnt drains, NO fences ever.
// All cross-block traffic via per-access agent-scope atomics (sc1 -> MALL).
__device__ int   g_ticket;
__device__ float g_chunkB[GMAX * STATE];
__device__ float g_superB[64 * STATE];

__device__ __forceinline__ unsigned short f2bf(float x) {
  unsigned u = __float_as_uint(x);
  u += 0x7fffu + ((u >> 16) & 1u);   // round-to-nearest-even
  return (unsigned short)(u >> 16);
}
__device__ __forceinline__ float bflo(unsigned u) { return __uint_as_float(u << 16); }
__device__ __forceinline__ float bfhi(unsigned u) { return __uint_as_float(u & 0xffff0000u); }

__device__ __forceinline__ void st_agent(float* p, float v) {
  __hip_atomic_store(p, v, __ATOMIC_RELAXED, __HIP_MEMORY_SCOPE_AGENT);
}
__device__ __forceinline__ float ld_agent(const float* p) {
  return __hip_atomic_load(p, __ATOMIC_RELAXED, __HIP_MEMORY_SCOPE_AGENT);
}

// Block b owns chunks 2b (events/slots 0..255) and 2b+1 (256..511).
// 1024 threads: e = tid>>1 (event), h = tid&1 (mark-half / slot-parity).
// Chain identity: S_B = dA*(S_A + totA)  (t_ref(B) == te(A)).
__global__ __launch_bounds__(1024) void hawkes_df2(
    const float* __restrict__ ti, const int* __restrict__ mi,
    const float* __restrict__ mu, const float* __restrict__ alpha,
    const float* __restrict__ gamma, float* __restrict__ out,
    int N, int G, int NB) {
  int tid = threadIdx.x;
  __shared__ int vid_s;
  __shared__ unsigned P0[MM * ASTRIDE];          // bf16x2 {k0,k1} of gamma_k*alpha
  __shared__ unsigned P1[MM * ASTRIDE];          // bf16x2 {k2,k3}
  __shared__ __align__(16) float4 Fj[512];       // exp(+gk*(t_j - tref_ch))
  __shared__ int   cj[512];
  __shared__ __align__(16) float Q[16][STATE];   // buckets -> W levels (S folded in)
  __shared__ float SB1[STATE];                   // odd-chunk gather partial
  __shared__ float SB2[STATE];                   // even-super gather partial
  __shared__ float SB3[STATE];                   // odd-super gather partial
  __shared__ float teL[SUP];                     // end times of chunks g0c..g0c+31
  __shared__ float tlast[NSMAX];                 // end times of supers 0..sup-1
  __shared__ float red16[16];

  if (tid == 0) vid_s = atomicAdd(&g_ticket, 1);

  int b = blockIdx.x;
  int c0 = 2 * b;
  int lQ = c0 * CHUNK;
  int sup = b >> 4;                 // 16 blocks = 32 chunks = 1 super
  int g0c = sup * SUP;
  int nloc = c0 - g0c;              // 0..30, even
  int e = tid >> 1;                 // event slot 0..511
  int h = tid & 1;                  // half
  int ch = e >> 8;                  // 0 = chunk A, 1 = chunk B

  float gk0 = gamma[0], gk1 = gamma[1], gk2 = gamma[2], gk3 = gamma[3];

  for (int i = tid; i < 16 * STATE; i += 1024) ((float*)Q)[i] = 0.f;
  if (tid < SUP) {
    int c = g0c + tid;
    if (c < G) teL[tid] = ti[min(N, (c + 1) * CHUNK) - 1];
  } else if (tid >= 64 && tid < 64 + NSMAX) {
    int s = tid - 64;
    if (s < sup) tlast[s] = ti[min(N, (s + 1) * SUP * CHUNK) - 1];
  }
  if (b == 0 && tid == 0) st_agent(out, 0.f);

  // staging: event n = lQ+e (pair-shared loads hit same line); source j = n-1
  float tref0 = ti[(b == 0) ? 0 : (lQ - 1)];
  float tref_ch = ch ? ti[min(N - 1, lQ + CHUNK - 1)] : tref0;
  int n = lQ + e;
  bool has_n = (n < N);
  float ti_n = has_n ? ti[n] : 0.f;
  int   mi_n = has_n ? mi[n] : 0;
  float mu_n = has_n ? mu[n] : 0.f;
  int j = n - 1;
  float ti_j = __shfl_up(ti_n, 2, 64);   // lane-2 holds event e-1
  int   mi_j = __shfl_up(mi_n, 2, 64);
  if ((tid & 63) < 2 && j >= 0) { ti_j = ti[j]; mi_j = mi[j]; }
  bool valid = (j >= 0) && has_n;
  int myc = valid ? mi_j : 0;
  float ga = h ? gk2 : gk0, gb = h ? gk3 : gk1;
  float2 F2 = make_float2(0.f, 0.f);
  if (valid) {
    float tj = ti_j - tref_ch;
    F2 = make_float2(__expf(ga * tj), __expf(gb * tj));   // 2 exps/lane (split)
  }
  if (h == 0) cj[e] = myc;
  ((float2*)&Fj[e])[h] = F2;
  __syncthreads();   // B1: Q zeroed, events staged, teL/tlast/vid ready

  // buckets (2 atomics/lane) + P staging (loads overlap the LDS atomics)
  if (valid) {
    float* q = &Q[e >> 5][myc * KK + 2 * h];
    atomicAdd(q + 0, F2.x); atomicAdd(q + 1, F2.y);
  }
  #pragma unroll
  for (int u = 0; u < 3; ++u) {
    int idx = tid + 1024 * u;
    if (idx < MM * MM) {
      int c = idx / MM, cp = idx - c * MM;
      float a0 = gk0 * alpha[idx];
      float a1 = gk1 * alpha[2500 + idx];
      float a2 = gk2 * alpha[5000 + idx];
      float a3 = gk3 * alpha[7500 + idx];
      P0[c * ASTRIDE + cp] = (unsigned)f2bf(a0) | ((unsigned)f2bf(a1) << 16);
      P1[c * ASTRIDE + cp] = (unsigned)f2bf(a2) | ((unsigned)f2bf(a3) << 16);
    }
  }
  __syncthreads();   // B2: buckets + P complete

  float epoch_s = ((vid_s / NB) & 1) ? -1.f : 1.f;
  float gkc = (tid & 2) ? ((tid & 1) ? gk3 : gk2) : ((tid & 1) ? gk1 : gk0);
  float totA = 0.f, totB = 0.f, dA = 0.f, dB = 0.f;
  if (tid < STATE) {   // publish both chunk summaries IMMEDIATELY (fire & forget)
    #pragma unroll
    for (int q = 0; q < 8; ++q)  totA += Q[q][tid];
    #pragma unroll
    for (int q = 8; q < 16; ++q) totB += Q[q][tid];
    dA = __expf(-gkc * (teL[nloc] - tref0));
    dB = __expf(-gkc * (teL[nloc + 1] - teL[nloc]));
    st_agent(&g_chunkB[(size_t)c0 * STATE + tid], epoch_s * (dA * totA + 1.f));
    st_agent(&g_chunkB[(size_t)(c0 + 1) * STATE + tid], epoch_s * (dB * totB + 1.f));
  }

  // pairwise contraction, parity-split slots (~8 iters/lane): overlaps publishes
  float4 acc = make_float4(0.f, 0.f, 0.f, 0.f);
  int rowb = mi_n * ASTRIDE;
  if (has_n) {
    int base = e & ~31;               // wave-uniform (one sub-chunk per wave)
    #pragma unroll 4
    for (int s = base + h; s <= e; s += 2) {
      unsigned p0 = P0[rowb + cj[s]];
      unsigned p1 = P1[rowb + cj[s]];
      float4 f = Fj[s];
      acc.x += bflo(p0) * f.x; acc.y += bfhi(p0) * f.y;
      acc.z += bflo(p1) * f.z; acc.w += bfhi(p1) * f.w;
    }
  }

  // ---- dataflow gathers: FOUR disjoint 200-thread groups run CONCURRENTLY
  bool closer = ((b & 15) == 15) || (b == NB - 1);
  bool grpA = (tid < STATE);
  bool grpB = (tid >= 256) && (tid < 256 + STATE);
  bool grpC = (tid >= 512) && (tid < 512 + STATE);
  bool grpD = (tid >= 768) && (tid < 768 + STATE);
  int st = tid & 255;                 // state index within group (bases % 4 == 0)
  float SA = 0.f;
  int cpar = nloc >> 1;               // even == odd count (<=15)
  int cse = (sup + 1) >> 1, cso = sup >> 1;

  if (grpA && cpar) {                 // even intra chunks
    float r[15];
    #pragma unroll
    for (int i = 0; i < 15; ++i)
      r[i] = (i < cpar) ? ld_agent(&g_chunkB[(size_t)(g0c + 2 * i) * STATE + st]) : epoch_s;
    #pragma unroll
    for (int i = 0; i < 15; ++i) if (i < cpar) {
      float v = r[i];
      while (epoch_s * v < 0.5f) {
        __builtin_amdgcn_s_sleep(1);
        v = ld_agent(&g_chunkB[(size_t)(g0c + 2 * i) * STATE + st]);
      }
      SA += __expf(-gkc * (tref0 - teL[2 * i])) * (epoch_s * v - 1.f);
    }
  }
  if (grpB) {                         // odd intra chunks
    float PB = 0.f;
    if (cpar) {
      float r[15];
      #pragma unroll
      for (int i = 0; i < 15; ++i)
        r[i] = (i < cpar) ? ld_agent(&g_chunkB[(size_t)(g0c + 2 * i + 1) * STATE + st]) : epoch_s;
      #pragma unroll
      for (int i = 0; i < 15; ++i) if (i < cpar) {
        float v = r[i];
        while (epoch_s * v < 0.5f) {
          __builtin_amdgcn_s_sleep(1);
          v = ld_agent(&g_chunkB[(size_t)(g0c + 2 * i + 1) * STATE + st]);
        }
        PB += __expf(-gkc * (tref0 - teL[2 * i + 1])) * (epoch_s * v - 1.f);
      }
    }
    SB1[st] = PB;
  }
  if (grpC) {                         // even supers (concurrent with chunk gathers)
    float PC = 0.f;
    if (cse) {
      float r[13];
      #pragma unroll
      for (int i = 0; i < 13; ++i)
        r[i] = (i < cse) ? ld_agent(&g_superB[(size_t)(2 * i) * STATE + st]) : epoch_s;
      #pragma unroll
      for (int i = 0; i < 13; ++i) if (i < cse) {
        float v = r[i];
        while (epoch_s * v < 0.5f) {
          __builtin_amdgcn_s_sleep(1);
          v = ld_agent(&g_superB[(size_t)(2 * i) * STATE + st]);
        }
        PC += __expf(-gkc * (tref0 - tlast[2 * i])) * (epoch_s * v - 1.f);
      }
    }
    SB2[st] = PC;
  }
  if (grpD) {                         // odd supers
    float PD = 0.f;
    if (cso) {
      float r[12];
      #pragma unroll
      for (int i = 0; i < 12; ++i)
        r[i] = (i < cso) ? ld_agent(&g_superB[(size_t)(2 * i + 1) * STATE + st]) : epoch_s;
      #pragma unroll
      for (int i = 0; i < 12; ++i) if (i < cso) {
        float v = r[i];
        while (epoch_s * v < 0.5f) {
          __builtin_amdgcn_s_sleep(1);
          v = ld_agent(&g_superB[(size_t)(2 * i + 1) * STATE + st]);
        }
        PD += __expf(-gkc * (tref0 - tlast[2 * i + 1])) * (epoch_s * v - 1.f);
      }
    }
    SB3[st] = PD;
  }

  if (closer) {
    __syncthreads();   // C1: SB1 ready (block-uniform branch: legal)
    if (grpA) {
      float Sin = SA + SB1[st];       // full intra sum anchored tref0
      float run2 = dA * (Sin + totA);
      run2 = dB * (run2 + totB);
      st_agent(&g_superB[(size_t)sup * STATE + st], epoch_s * (run2 + 1.f));
      SA = Sin;                       // SB1 folded in: don't re-add
    }
  }
  __syncthreads();   // B3: all gather partials ready

  if (grpA) {
    float S = SA + SB2[st] + SB3[st] + (closer ? 0.f : SB1[st]);
    // W levels with S folded in: Q[q] <- running prefix (A then B chained)
    float run = S;
    #pragma unroll
    for (int q = 0; q < 8; ++q)  { float t = Q[q][st]; Q[q][st] = run; run += t; }
    run = dA * run;   // S_B = dA*(S_A + totA)
    #pragma unroll
    for (int q = 8; q < 16; ++q) { float t = Q[q][st]; Q[q][st] = run; run += t; }
  }
  __syncthreads();   // B4: W levels ready

  // prefix contraction over marks, h-split (25 iters/lane) + combine + finalize
  float local = 0.f;
  if (has_n) {
    const float4* wb = (const float4*)&Q[e >> 5][0];   // wave-uniform row
    int mlo = h * 25, mhi = mlo + 25;
    #pragma unroll 5
    for (int m = mlo; m < mhi; ++m) {
      unsigned p0 = P0[rowb + m];
      unsigned p1 = P1[rowb + m];
      float4 w = wb[m];
      acc.x += bflo(p0) * w.x; acc.y += bfhi(p0) * w.y;
      acc.z += bflo(p1) * w.z; acc.w += bfhi(p1) * w.w;
    }
  }
  acc.x += __shfl_xor(acc.x, 1, 64);   // merge h-halves (pairwise parity + marks)
  acc.y += __shfl_xor(acc.y, 1, 64);
  acc.z += __shfl_xor(acc.z, 1, 64);
  acc.w += __shfl_xor(acc.w, 1, 64);
  if (h == 0 && has_n) {
    float tn = ti_n - tref_ch;
    float lam = mu_n
              + __expf(-gk0 * tn) * acc.x + __expf(-gk1 * tn) * acc.y
              + __expf(-gk2 * tn) * acc.z + __expf(-gk3 * tn) * acc.w;
    local = __logf(lam);
  }
  #pragma unroll
  for (int off = 32; off > 0; off >>= 1)
    local += __shfl_down(local, off, 64);
  if ((tid & 63) == 0) red16[tid >> 6] = local;
  __syncthreads();
  if (tid == 0) {
    float acc16 = 0.f;
    #pragma unroll
    for (int w = 0; w < 16; ++w) acc16 += red16[w];
    atomicAdd(out, acc16);
  }
}

extern "C" void kernel_launch(void* const* d_in, const int* in_sizes, int n_in,
                              void* d_out, int out_size, void* d_ws, size_t ws_size,
                              hipStream_t stream) {
  const float* ti    = (const float*)d_in[0];
  const int*   mi    = (const int*)d_in[1];
  const float* mu    = (const float*)d_in[2];
  const float* alpha = (const float*)d_in[3];
  const float* gamma = (const float*)d_in[4];
  float* out = (float*)d_out;
  int N = in_sizes[0];
  int G = (N + CHUNK - 1) / CHUNK;
  if (G > GMAX) return;   // problem is fixed at N=200000 (G=782); guard OOB
  int NB = (G + 1) / 2;   // 391 blocks, 2 chunks each, 1024 threads

  hawkes_df2<<<NB, 1024, 0, stream>>>(ti, mi, mu, alpha, gamma, out, N, G, NB);
}

// Round 11
// 84.539 us; speedup vs baseline: 1.1972x; 1.1972x over previous
//
#include <hip/hip_runtime.h>

#define CHUNK 256
#define MM 50
#define KK 4
#define STATE 200       // MM*KK
#define ASTRIDE 51      // odd WORD stride
#define SUP 32          // chunks per super-chunk
#define NSMAX 26        // max super-chunks
#define GMAX 1024

// Dataflow protocol: publishers store epoch_s*(v+1) (v >= 0 always), readers
// poll until epoch_s*r >= 0.5. .bss zero-init = not-ready; sign flips per
// replay epoch so NO resets, NO flags, NO vmcnt drains, NO fences ever.
// All cross-block traffic via per-access agent-scope atomics (sc1 -> MALL).
__device__ int   g_ticket;
__device__ float g_chunkB[GMAX * STATE];
__device__ float g_superB[64 * STATE];

__device__ __forceinline__ unsigned short f2bf(float x) {
  unsigned u = __float_as_uint(x);
  u += 0x7fffu + ((u >> 16) & 1u);   // round-to-nearest-even
  return (unsigned short)(u >> 16);
}
__device__ __forceinline__ float bflo(unsigned u) { return __uint_as_float(u << 16); }
__device__ __forceinline__ float bfhi(unsigned u) { return __uint_as_float(u & 0xffff0000u); }

__device__ __forceinline__ void st_agent(float* p, float v) {
  __hip_atomic_store(p, v, __ATOMIC_RELAXED, __HIP_MEMORY_SCOPE_AGENT);
}
__device__ __forceinline__ float ld_agent(const float* p) {
  return __hip_atomic_load(p, __ATOMIC_RELAXED, __HIP_MEMORY_SCOPE_AGENT);
}

// Block b owns chunks 2b (A: slots 0..255) and 2b+1 (B: slots 256..511).
// Chain identity: S_B = dA*(S_A + totA)  (t_ref(B) == te(A)).
__global__ __launch_bounds__(512) void hawkes_df(
    const float* __restrict__ ti, const int* __restrict__ mi,
    const float* __restrict__ mu, const float* __restrict__ alpha,
    const float* __restrict__ gamma, float* __restrict__ out,
    int N, int G, int NB) {
  int tid = threadIdx.x;
  __shared__ int vid_s;
  __shared__ unsigned P0[MM * ASTRIDE];          // bf16x2 {k0,k1} of gamma_k*alpha
  __shared__ unsigned P1[MM * ASTRIDE];          // bf16x2 {k2,k3}
  __shared__ __align__(16) float4 Fj[512];       // exp(+gk*(t_j - tref_ch))
  __shared__ int   cj[512];
  __shared__ __align__(16) float Q[16][STATE];   // buckets -> W levels (S folded in)
  __shared__ float SB1[STATE];                   // group-B partial (odd chunks)
  __shared__ float SB2[STATE];                   // group-B partial (odd supers)
  __shared__ float teL[SUP];                     // end times of chunks g0c..g0c+31
  __shared__ float tlast[NSMAX];                 // end times of supers 0..sup-1
  __shared__ float red8[8];

  if (tid == 0) vid_s = atomicAdd(&g_ticket, 1);

  int b = blockIdx.x;
  int c0 = 2 * b;
  int lQ = c0 * CHUNK;
  int sup = b >> 4;                 // 16 blocks = 32 chunks = 1 super
  int g0c = sup * SUP;
  int nloc = c0 - g0c;              // 0..30, even
  int ch = tid >> 8;                // 0 = chunk A, 1 = chunk B

  float gk0 = gamma[0], gk1 = gamma[1], gk2 = gamma[2], gk3 = gamma[3];

  for (int i = tid; i < 16 * STATE; i += 512) ((float*)Q)[i] = 0.f;
  if (tid < SUP) {
    int c = g0c + tid;
    if (c < G) teL[tid] = ti[min(N, (c + 1) * CHUNK) - 1];
  } else if (tid >= 64 && tid < 64 + NSMAX) {
    int s = tid - 64;
    if (s < sup) tlast[s] = ti[min(N, (s + 1) * SUP * CHUNK) - 1];
  }
  if (b == 0 && tid == 0) st_agent(out, 0.f);

  // single-load staging: this thread's event n; source j = n-1 via shuffle
  float tref0 = ti[(b == 0) ? 0 : (lQ - 1)];
  float tref_ch = ch ? ti[min(N - 1, lQ + CHUNK - 1)] : tref0;
  int n = lQ + tid;
  bool has_n = (n < N);
  float ti_n = has_n ? ti[n] : 0.f;
  int   mi_n = has_n ? mi[n] : 0;
  float mu_n = has_n ? mu[n] : 0.f;
  int j = lQ - 1 + tid;
  float ti_j = __shfl_up(ti_n, 1, 64);
  int   mi_j = __shfl_up(mi_n, 1, 64);
  if ((tid & 63) == 0 && j >= 0) { ti_j = ti[j]; mi_j = mi[j]; }
  bool valid = (j >= 0) && has_n;
  int myc = valid ? mi_j : 0;
  float4 F = make_float4(0.f, 0.f, 0.f, 0.f);
  if (valid) {
    float tj = ti_j - tref_ch;
    F = make_float4(__expf(gk0 * tj), __expf(gk1 * tj),
                    __expf(gk2 * tj), __expf(gk3 * tj));
  }
  cj[tid] = myc;
  Fj[tid] = F;
  __syncthreads();   // B1: Q zeroed, events staged, teL/tlast/vid ready

  // buckets + P staging (loads overlap the LDS atomics)
  if (valid) {
    float* q = &Q[tid >> 5][myc * KK];
    atomicAdd(q + 0, F.x); atomicAdd(q + 1, F.y);
    atomicAdd(q + 2, F.z); atomicAdd(q + 3, F.w);
  }
  #pragma unroll
  for (int u = 0; u < 5; ++u) {
    int idx = tid + 512 * u;
    if (idx < MM * MM) {
      int c = idx / MM, cp = idx - c * MM;
      float a0 = gk0 * alpha[idx];
      float a1 = gk1 * alpha[2500 + idx];
      float a2 = gk2 * alpha[5000 + idx];
      float a3 = gk3 * alpha[7500 + idx];
      P0[c * ASTRIDE + cp] = (unsigned)f2bf(a0) | ((unsigned)f2bf(a1) << 16);
      P1[c * ASTRIDE + cp] = (unsigned)f2bf(a2) | ((unsigned)f2bf(a3) << 16);
    }
  }
  __syncthreads();   // B2: buckets + P complete

  float epoch_s = ((vid_s / NB) & 1) ? -1.f : 1.f;
  float gkc = (tid & 2) ? ((tid & 1) ? gk3 : gk2) : ((tid & 1) ? gk1 : gk0);
  float totA = 0.f, totB = 0.f, dA = 0.f, dB = 0.f;
  if (tid < STATE) {   // publish both chunk summaries IMMEDIATELY (fire & forget)
    #pragma unroll
    for (int q = 0; q < 8; ++q)  totA += Q[q][tid];
    #pragma unroll
    for (int q = 8; q < 16; ++q) totB += Q[q][tid];
    dA = __expf(-gkc * (teL[nloc] - tref0));
    dB = __expf(-gkc * (teL[nloc + 1] - teL[nloc]));
    st_agent(&g_chunkB[(size_t)c0 * STATE + tid], epoch_s * (dA * totA + 1.f));
    st_agent(&g_chunkB[(size_t)(c0 + 1) * STATE + tid], epoch_s * (dB * totB + 1.f));
  }

  // pairwise contraction (needs no S): runs while publishes land grid-wide
  float4 acc = make_float4(0.f, 0.f, 0.f, 0.f);
  if (has_n) {
    int rowb = mi_n * ASTRIDE;
    int base = tid & ~31;
    #pragma unroll 4
    for (int s = base; s <= tid; ++s) {
      unsigned p0 = P0[rowb + cj[s]];
      unsigned p1 = P1[rowb + cj[s]];
      float4 f = Fj[s];
      acc.x += bflo(p0) * f.x; acc.y += bfhi(p0) * f.y;
      acc.z += bflo(p1) * f.z; acc.w += bfhi(p1) * f.w;
    }
  }

  // ---- dataflow gathers, parity-split; chunk AND super loads issued in one
  //      batch so the two MALL round trips overlap. Barriers stay BLOCK-UNIFORM
  //      at top level (round-10 bug: __syncthreads inside divergent groups).
  bool closer = ((b & 15) == 15) || (b == NB - 1);
  bool grpA = (tid < STATE);
  bool grpB = (tid >= 256) && (tid < 256 + STATE);
  int st = tid & 255;     // state index per group (group bases 0 and 256)
  float SA = 0.f;
  int cpar = nloc >> 1;   // nloc even: #even-u == #odd-u == nloc/2 (<=15)
  int cse = (sup + 1) >> 1, cso = sup >> 1;   // even/odd super counts (<=13/12)

  float rc[15], rs[13];
  // issue phase: both levels in flight at once
  if (grpA) {
    #pragma unroll
    for (int i = 0; i < 15; ++i)
      rc[i] = (i < cpar) ? ld_agent(&g_chunkB[(size_t)(g0c + 2 * i) * STATE + st]) : epoch_s;
    #pragma unroll
    for (int i = 0; i < 13; ++i)
      rs[i] = (i < cse) ? ld_agent(&g_superB[(size_t)(2 * i) * STATE + st]) : epoch_s;
  } else if (grpB) {
    #pragma unroll
    for (int i = 0; i < 15; ++i)
      rc[i] = (i < cpar) ? ld_agent(&g_chunkB[(size_t)(g0c + 2 * i + 1) * STATE + st]) : epoch_s;
    #pragma unroll
    for (int i = 0; i < 13; ++i)
      rs[i] = (i < cso) ? ld_agent(&g_superB[(size_t)(2 * i + 1) * STATE + st]) : epoch_s;
  }
  // poll chunk level
  if (grpA) {
    #pragma unroll
    for (int i = 0; i < 15; ++i) if (i < cpar) {
      float v = rc[i];
      while (epoch_s * v < 0.5f) {
        __builtin_amdgcn_s_sleep(1);
        v = ld_agent(&g_chunkB[(size_t)(g0c + 2 * i) * STATE + st]);
      }
      SA += __expf(-gkc * (tref0 - teL[2 * i])) * (epoch_s * v - 1.f);
    }
  } else if (grpB) {
    float PB = 0.f;
    #pragma unroll
    for (int i = 0; i < 15; ++i) if (i < cpar) {
      float v = rc[i];
      while (epoch_s * v < 0.5f) {
        __builtin_amdgcn_s_sleep(1);
        v = ld_agent(&g_chunkB[(size_t)(g0c + 2 * i + 1) * STATE + st]);
      }
      PB += __expf(-gkc * (tref0 - teL[2 * i + 1])) * (epoch_s * v - 1.f);
    }
    SB1[st] = PB;
  }

  if (closer) __syncthreads();   // C1: block-uniform; SB1 ready for the publish
  if (closer && grpA) {          // rs[] stays live in registers across C1
    float Sin = SA + SB1[st];    // full intra sum anchored tref0
    float run2 = dA * (Sin + totA);
    run2 = dB * (run2 + totB);
    st_agent(&g_superB[(size_t)sup * STATE + st], epoch_s * (run2 + 1.f));
    SA = Sin;                    // SB1 folded in: don't re-add
  }

  // poll super level (loads issued long ago -> usually already resolved)
  if (grpA) {
    #pragma unroll
    for (int i = 0; i < 13; ++i) if (i < cse) {
      float v = rs[i];
      while (epoch_s * v < 0.5f) {
        __builtin_amdgcn_s_sleep(1);
        v = ld_agent(&g_superB[(size_t)(2 * i) * STATE + st]);
      }
      SA += __expf(-gkc * (tref0 - tlast[2 * i])) * (epoch_s * v - 1.f);
    }
  } else if (grpB) {
    float PB2 = 0.f;
    #pragma unroll
    for (int i = 0; i < 13; ++i) if (i < cso) {
      float v = rs[i];
      while (epoch_s * v < 0.5f) {
        __builtin_amdgcn_s_sleep(1);
        v = ld_agent(&g_superB[(size_t)(2 * i + 1) * STATE + st]);
      }
      PB2 += __expf(-gkc * (tref0 - tlast[2 * i + 1])) * (epoch_s * v - 1.f);
    }
    SB2[st] = PB2;
  }
  __syncthreads();   // C2: all partials ready

  if (grpA) {
    float S = SA + SB2[st] + (closer ? 0.f : SB1[st]);
    // W levels with S folded in: Q[q] <- running prefix (A then B chained)
    float run = S;
    #pragma unroll
    for (int q = 0; q < 8; ++q)  { float t = Q[q][st]; Q[q][st] = run; run += t; }
    run = dA * run;   // S_B = dA*(S_A + totA)
    #pragma unroll
    for (int q = 8; q < 16; ++q) { float t = Q[q][st]; Q[q][st] = run; run += t; }
  }
  __syncthreads();   // B3: W levels ready

  // prefix contraction over marks + finalize
  float local = 0.f;
  if (has_n) {
    int rowb = mi_n * ASTRIDE;
    const float4* wb = (const float4*)&Q[tid >> 5][0];
    #pragma unroll 10
    for (int m = 0; m < MM; ++m) {
      unsigned p0 = P0[rowb + m];
      unsigned p1 = P1[rowb + m];
      float4 w = wb[m];
      acc.x += bflo(p0) * w.x; acc.y += bfhi(p0) * w.y;
      acc.z += bflo(p1) * w.z; acc.w += bfhi(p1) * w.w;
    }
    float tn = ti_n - tref_ch;
    float lam = mu_n
              + __expf(-gk0 * tn) * acc.x + __expf(-gk1 * tn) * acc.y
              + __expf(-gk2 * tn) * acc.z + __expf(-gk3 * tn) * acc.w;
    local = __logf(lam);
  }
  #pragma unroll
  for (int off = 32; off > 0; off >>= 1)
    local += __shfl_down(local, off, 64);
  if ((tid & 63) == 0) red8[tid >> 6] = local;
  __syncthreads();
  if (tid == 0) {
    float acc8 = 0.f;
    #pragma unroll
    for (int w = 0; w < 8; ++w) acc8 += red8[w];
    atomicAdd(out, acc8);
  }
}

extern "C" void kernel_launch(void* const* d_in, const int* in_sizes, int n_in,
                              void* d_out, int out_size, void* d_ws, size_t ws_size,
                              hipStream_t stream) {
  const float* ti    = (const float*)d_in[0];
  const int*   mi    = (const int*)d_in[1];
  const float* mu    = (const float*)d_in[2];
  const float* alpha = (const float*)d_in[3];
  const float* gamma = (const float*)d_in[4];
  float* out = (float*)d_out;
  int N = in_sizes[0];
  int G = (N + CHUNK - 1) / CHUNK;
  if (G > GMAX) return;   // problem is fixed at N=200000 (G=782); guard OOB
  int NB = (G + 1) / 2;   // 391 blocks, 2 chunks each

  hawkes_df<<<NB, 512, 0, stream>>>(ti, mi, mu, alpha, gamma, out, N, G, NB);
}